// Round 7
// baseline (156.910 us; speedup 1.0000x reference)
//
#include <hip/hip_runtime.h>

// NWJ lower bound:
//   T1[i,j] = sum_k relu(xp[j,k] + yp[i,k] + b1[k]) * W2[k] + b2 - 1
//   bound   = mean_i T0[i] - (1/n^2) * sum_{ij} exp(T1[i,j]),  T0[i] = T1[i,i] + 1
// relu identity: relu(z) = (z + |z|)/2, so
//   T1[i,j] = 0.5*( R[j] + C[i] + sum_k |a_jk + c_ik| * w_k ) + b2 - 1
// with a = xp + b1 (At, transposed), c = yp (YpT, transposed),
//   R[j] = sum_k a_jk w_k,  C[i] = sum_k c_ik w_k   (rank-1, cheap).
// Inner loop is 2 VALU/element: v_add + v_fma with free |.| modifier.
// INVARIANT (R6 bug): JT == 256 threads * JPT. Block covers exactly its j-tile.

#define N_S  1024
#define XD   128
#define HIDD 256
#define JBLK 8     // sample rows per proj block
#define IBLK 8     // i-rows per pair block
#define JT   256   // j-cols per pair block == blockDim.x * JPT
#define JPT  1     // j per thread

// ---- Kernel 1: projections (both outputs transposed [HIDD][N_S]) -----------
// which=0: At[k][j]  = (x@Wx)[j,k] + b1[k]
// which=1: YpT[k][i] = (y@Wy)[i,k]
__global__ __launch_bounds__(256) void proj_kernel(
    const float* __restrict__ x, const float* __restrict__ y,
    const float* __restrict__ W1, const float* __restrict__ b1,
    float* __restrict__ At, float* __restrict__ YpT) {
  const int k     = threadIdx.x;        // hidden index 0..255
  const int which = blockIdx.y;
  const int r0    = blockIdx.x * JBLK;  // sample base

  __shared__ float s_in[JBLK][XD];      // 4 KB
  const float* src = which ? y : x;
  for (int t = k; t < JBLK * XD; t += 256)
    s_in[t >> 7][t & 127] = src[r0 * XD + t];     // rows contiguous, coalesced
  __syncthreads();

  const float* W = W1 + (which ? XD * HIDD : 0);
  float acc[JBLK];
  #pragma unroll
  for (int r = 0; r < JBLK; ++r) acc[r] = 0.f;

  #pragma unroll 4
  for (int d = 0; d < XD; ++d) {
    const float w = W[d * HIDD + k];              // coalesced across k
    #pragma unroll
    for (int r = 0; r < JBLK; ++r)
      acc[r] = fmaf(s_in[r][d], w, acc[r]);       // LDS broadcast
  }

  // transpose via LDS so global writes are contiguous segments
  const float bk = which ? 0.f : b1[k];
  float* dst = which ? YpT : At;
  __shared__ float s_t[HIDD][JBLK + 1];           // 9 KB, pad -> low conflicts
  #pragma unroll
  for (int r = 0; r < JBLK; ++r) s_t[k][r] = acc[r] + bk;
  __syncthreads();
  const int jj = k & (JBLK - 1);                  // 0..7
  const int kk = k >> 3;                          // 0..31
  #pragma unroll
  for (int m = 0; m < JBLK; ++m) {
    const int kr = m * 32 + kk;
    dst[kr * N_S + r0 + jj] = s_t[kr][jj];        // 8 consecutive j per k
  }
}

// ---- Kernel 2: rank-1 terms R[j], C[i] -------------------------------------
__global__ __launch_bounds__(256) void rank1_kernel(
    const float* __restrict__ At, const float* __restrict__ YpT,
    const float* __restrict__ W2, float* __restrict__ R, float* __restrict__ C) {
  const int b = blockIdx.x;                       // 0..7
  const int j = (b & 3) * 256 + threadIdx.x;
  const float* src = (b < 4) ? At : YpT;
  float s0 = 0.f, s1 = 0.f, s2 = 0.f, s3 = 0.f;
  #pragma unroll 4
  for (int k = 0; k < HIDD; k += 4) {             // coalesced, W2 scalar
    s0 = fmaf(src[(k + 0) * N_S + j], W2[k + 0], s0);
    s1 = fmaf(src[(k + 1) * N_S + j], W2[k + 1], s1);
    s2 = fmaf(src[(k + 2) * N_S + j], W2[k + 2], s2);
    s3 = fmaf(src[(k + 3) * N_S + j], W2[k + 3], s3);
  }
  ((b < 4) ? R : C)[j] = (s0 + s1) + (s2 + s3);
}

// ---- Kernel 3: pairwise |z|-dot, exp-sum, diagonal -------------------------
// Block: IBLK i-rows x JT j-cols; thread owns ONE j, streams k.
// i-side operands are wave-uniform -> scalar (SMEM) loads, no LDS in hot loop.
__global__ __launch_bounds__(256, 4) void pair2_kernel(
    const float* __restrict__ At, const float* __restrict__ YpT,
    const float* __restrict__ W2, const float* __restrict__ R,
    const float* __restrict__ C, const float* __restrict__ b2,
    float2* __restrict__ partial) {
  const int tid = threadIdx.x;
  const int ib  = blockIdx.x >> 2;        // 0..127  (N_S/JT = 4 j-tiles)
  const int jt  = blockIdx.x & 3;         // 0..3
  const int i0  = ib * IBLK;
  const int j   = jt * JT + tid;          // one j per thread

  float acc[IBLK];
  #pragma unroll
  for (int ii = 0; ii < IBLK; ++ii) acc[ii] = 0.f;

  const float* ap = At + j;
  #pragma unroll 8
  for (int k = 0; k < HIDD; ++k) {
    const float a = ap[k * N_S];                      // coalesced dword
    const float w = W2[k];                            // uniform -> s_load
    const float* cr = YpT + k * N_S + i0;             // uniform -> s_load
    #pragma unroll
    for (int ii = 0; ii < IBLK; ++ii) {
      const float z = a + cr[ii];
      acc[ii] = fmaf(fabsf(z), w, acc[ii]);           // |.| = free modifier
    }
  }

  // epilogue: T1 = 0.5*(R[j] + C[i] + accAbs) + b2 - 1
  const float bb = b2[0] - 1.0f;
  const float Rj = R[j];
  float esum = 0.f, diag = 0.f;
  const int dd = j - i0;                  // diagonal: ii == dd
  #pragma unroll
  for (int ii = 0; ii < IBLK; ++ii) {
    const float Ci = C[i0 + ii];          // uniform scalar
    const float t  = fmaf(0.5f, Rj + Ci + acc[ii], bb);
    esum += __expf(t);
    if (ii == dd) diag += t;              // compile-time unrolled select
  }

  // wave reduce both, then cross-wave via LDS, one store per block
  #pragma unroll
  for (int m = 32; m >= 1; m >>= 1) {
    esum += __shfl_xor(esum, m, 64);
    diag += __shfl_xor(diag, m, 64);
  }
  __shared__ float s_es[4], s_dg[4];
  const int wave = tid >> 6, lane = tid & 63;
  if (lane == 0) { s_es[wave] = esum; s_dg[wave] = diag; }
  __syncthreads();
  if (tid == 0)
    partial[blockIdx.x] = make_float2(s_es[0] + s_es[1] + s_es[2] + s_es[3],
                                      s_dg[0] + s_dg[1] + s_dg[2] + s_dg[3]);
}

// ---- Kernel 4: finalize (reduce 512 block partials in f64) -----------------
__global__ __launch_bounds__(256) void finalize_kernel(
    const float2* __restrict__ partial, float* __restrict__ out) {
  const int tid = threadIdx.x;
  double es = 0.0, dg = 0.0;
  #pragma unroll
  for (int t = 0; t < 2; ++t) {
    const float2 p = partial[tid + 256 * t];
    es += (double)p.x; dg += (double)p.y;
  }
  #pragma unroll
  for (int m = 32; m >= 1; m >>= 1) {
    es += __shfl_xor(es, m, 64);
    dg += __shfl_xor(dg, m, 64);
  }
  __shared__ double s_es[4], s_dg[4];
  const int wave = tid >> 6, lane = tid & 63;
  if (lane == 0) { s_es[wave] = es; s_dg[wave] = dg; }
  __syncthreads();
  if (tid == 0) {
    const double esT = s_es[0] + s_es[1] + s_es[2] + s_es[3];
    const double dgT = s_dg[0] + s_dg[1] + s_dg[2] + s_dg[3];
    const double n = (double)N_S;
    // mean T0 = diag(T1)/n + 1 ; term2 = expsum / n^2
    out[0] = (float)(dgT / n + 1.0 - esT / (n * n));
  }
}

extern "C" void kernel_launch(void* const* d_in, const int* in_sizes, int n_in,
                              void* d_out, int out_size, void* d_ws, size_t ws_size,
                              hipStream_t stream) {
  const float* x  = (const float*)d_in[0];
  const float* y  = (const float*)d_in[1];
  const float* W1 = (const float*)d_in[2];
  const float* b1 = (const float*)d_in[3];
  const float* W2 = (const float*)d_in[4];
  const float* b2 = (const float*)d_in[5];

  float*  At      = (float*)d_ws;                 // [HIDD][N_S]   1 MB
  float*  YpT     = At + HIDD * N_S;              // [HIDD][N_S]   1 MB
  float*  R       = YpT + HIDD * N_S;             // [N_S]
  float*  C       = R + N_S;                      // [N_S]
  float2* partial = (float2*)(C + N_S);           // 512 float2    4 KB

  dim3 g1(N_S / JBLK, 2);                         // 128 x 2 blocks
  proj_kernel<<<g1, 256, 0, stream>>>(x, y, W1, b1, At, YpT);
  rank1_kernel<<<8, 256, 0, stream>>>(At, YpT, W2, R, C);
  pair2_kernel<<<(N_S / IBLK) * (N_S / JT), 256, 0, stream>>>(At, YpT, W2, R, C, b2, partial);
  finalize_kernel<<<1, 256, 0, stream>>>(partial, (float*)d_out);
}

// Round 8
// 108.756 us; speedup vs baseline: 1.4428x; 1.4428x over previous
//
#include <hip/hip_runtime.h>

// NWJ lower bound:
//   T1[i,j] = sum_k relu(xp[j,k] + yp[i,k] + b1[k]) * W2[k] + b2 - 1
//   bound   = mean_i T0[i] - (1/n^2) * sum_{ij} exp(T1[i,j]),  T0[i] = T1[i,i] + 1
// relu identity: relu(z) = (z + |z|)/2, so
//   T1[i,j] = 0.5*( R[j] + C[i] + sum_k |a_jk + c_ik| * w_k ) + b2 - 1
// with a = xp + b1 (At, transposed [HIDD][N_S]), c = yp (Yp, row-major [N_S][HIDD]),
//   R[j] = sum_k a_jk w_k,  C[i] = sum_k c_ik w_k   (rank-1, cheap).
// Inner loop: 2 VALU/element; i-side + w2 via LDS BROADCAST (not SMEM — R7 lesson:
// s_load chains serialize the loop at ~200cy each; ds_read broadcasts pipeline).

#define N_S  1024
#define XD   128
#define HIDD 256
#define JBLK 8     // sample rows per proj block
#define IBLK 8     // i-rows per pair block
#define JT   256   // j-cols per pair block == blockDim.x (1 j per thread)

// ---- Kernel 1: projections --------------------------------------------------
// which=0: At[k][j] = (x@Wx)[j,k] + b1[k]   (transposed via LDS)
// which=1: Yp[i][k] = (y@Wy)[i,k]           (row-major, direct coalesced write)
__global__ __launch_bounds__(256) void proj_kernel(
    const float* __restrict__ x, const float* __restrict__ y,
    const float* __restrict__ W1, const float* __restrict__ b1,
    float* __restrict__ At, float* __restrict__ Yp) {
  const int k     = threadIdx.x;        // hidden index 0..255
  const int which = blockIdx.y;
  const int r0    = blockIdx.x * JBLK;  // sample base

  __shared__ float s_in[JBLK][XD];                // 4 KB
  __shared__ float s_t[HIDD][JBLK + 1];           // 9 KB (used only for which=0)

  const float* src = which ? y : x;
  for (int t = k; t < JBLK * XD; t += 256)
    s_in[t >> 7][t & 127] = src[r0 * XD + t];     // rows contiguous, coalesced
  __syncthreads();

  const float* W = W1 + (which ? XD * HIDD : 0);
  float acc[JBLK];
  #pragma unroll
  for (int r = 0; r < JBLK; ++r) acc[r] = 0.f;

  #pragma unroll 4
  for (int d = 0; d < XD; ++d) {
    const float w = W[d * HIDD + k];              // coalesced across k
    #pragma unroll
    for (int r = 0; r < JBLK; ++r)
      acc[r] = fmaf(s_in[r][d], w, acc[r]);       // LDS broadcast
  }

  if (which) {
    #pragma unroll
    for (int r = 0; r < JBLK; ++r)
      Yp[(r0 + r) * HIDD + k] = acc[r];           // coalesced row-major
  } else {
    // transpose via LDS so At writes go out as contiguous segments
    const float bk = b1[k];
    #pragma unroll
    for (int r = 0; r < JBLK; ++r) s_t[k][r] = acc[r] + bk;
    __syncthreads();
    const int jj = k & (JBLK - 1);                // 0..7
    const int kk = k >> 3;                        // 0..31
    #pragma unroll
    for (int m = 0; m < JBLK; ++m) {
      const int kr = m * 32 + kk;
      At[kr * N_S + r0 + jj] = s_t[kr][jj];       // 8 consecutive j per k
    }
  }
}

// ---- Kernel 2: rank-1 terms R[j] (from At) and C[i] (from Yp) --------------
__global__ __launch_bounds__(256) void rank1_kernel(
    const float* __restrict__ At, const float* __restrict__ Yp,
    const float* __restrict__ W2, float* __restrict__ R, float* __restrict__ C) {
  const int b   = blockIdx.x;                     // 0..7
  const int tid = threadIdx.x;
  if (b < 4) {                                    // R[j]: coalesced down At cols
    const int j = b * 256 + tid;
    float s0 = 0.f, s1 = 0.f, s2 = 0.f, s3 = 0.f;
    #pragma unroll 4
    for (int k = 0; k < HIDD; k += 4) {
      s0 = fmaf(At[(k + 0) * N_S + j], W2[k + 0], s0);
      s1 = fmaf(At[(k + 1) * N_S + j], W2[k + 1], s1);
      s2 = fmaf(At[(k + 2) * N_S + j], W2[k + 2], s2);
      s3 = fmaf(At[(k + 3) * N_S + j], W2[k + 3], s3);
    }
    R[j] = (s0 + s1) + (s2 + s3);
  } else {                                        // C[i]: per-thread row, float4
    const int i = (b - 4) * 256 + tid;
    const float4* yrow = (const float4*)(Yp + i * HIDD);
    const float4* w4   = (const float4*)W2;       // uniform -> s_load
    float s0 = 0.f, s1 = 0.f, s2 = 0.f, s3 = 0.f;
    #pragma unroll 8
    for (int q = 0; q < HIDD / 4; ++q) {
      const float4 v = yrow[q];
      const float4 w = w4[q];
      s0 = fmaf(v.x, w.x, s0);
      s1 = fmaf(v.y, w.y, s1);
      s2 = fmaf(v.z, w.z, s2);
      s3 = fmaf(v.w, w.w, s3);
    }
    C[i] = (s0 + s1) + (s2 + s3);
  }
}

// ---- Kernel 3: pairwise |z|-dot, exp-sum, diagonal -------------------------
// Block: IBLK i-rows x JT j-cols; thread owns ONE j, streams k.
// i-side + w2 staged in LDS, read as uniform-address broadcasts (free).
__global__ __launch_bounds__(256, 2) void pair_kernel(
    const float* __restrict__ At, const float* __restrict__ Yp,
    const float* __restrict__ W2, const float* __restrict__ R,
    const float* __restrict__ C, const float* __restrict__ b2,
    float2* __restrict__ partial) {
  const int tid = threadIdx.x;
  const int ib  = blockIdx.x >> 2;        // 0..127  (N_S/JT = 4 j-tiles)
  const int jt  = blockIdx.x & 3;         // 0..3
  const int i0  = ib * IBLK;
  const int j   = jt * JT + tid;

  // one 48B row per k: [0..7] = yp^T (8 i-rows), [8] = w2[k]; rows 16B-aligned
  __shared__ float s_row[HIDD][12];       // 12 KB
  #pragma unroll
  for (int ii = 0; ii < IBLK; ++ii)
    s_row[tid][ii] = Yp[(i0 + ii) * HIDD + tid];  // coalesced global read
  s_row[tid][8] = W2[tid];
  __syncthreads();

  float acc[IBLK];
  #pragma unroll
  for (int ii = 0; ii < IBLK; ++ii) acc[ii] = 0.f;

  const float* ap = At + j;
  #pragma unroll 8
  for (int k = 0; k < HIDD; ++k) {
    const float  a  = ap[k * N_S];                     // coalesced dword
    const float4 y0 = *(const float4*)&s_row[k][0];    // broadcast b128
    const float4 y1 = *(const float4*)&s_row[k][4];    // broadcast b128
    const float  w  = s_row[k][8];                     // broadcast b32
    acc[0] = fmaf(fabsf(a + y0.x), w, acc[0]);         // |.| = free modifier
    acc[1] = fmaf(fabsf(a + y0.y), w, acc[1]);
    acc[2] = fmaf(fabsf(a + y0.z), w, acc[2]);
    acc[3] = fmaf(fabsf(a + y0.w), w, acc[3]);
    acc[4] = fmaf(fabsf(a + y1.x), w, acc[4]);
    acc[5] = fmaf(fabsf(a + y1.y), w, acc[5]);
    acc[6] = fmaf(fabsf(a + y1.z), w, acc[6]);
    acc[7] = fmaf(fabsf(a + y1.w), w, acc[7]);
  }

  // epilogue: T1 = 0.5*(R[j] + C[i] + accAbs) + b2 - 1
  const float bb = b2[0] - 1.0f;
  const float Rj = R[j];
  float esum = 0.f, diag = 0.f;
  const int dd = j - i0;                  // diagonal: ii == dd
  #pragma unroll
  for (int ii = 0; ii < IBLK; ++ii) {
    const float t = fmaf(0.5f, Rj + C[i0 + ii] + acc[ii], bb);
    esum += __expf(t);
    if (ii == dd) diag += t;              // compile-time unrolled select
  }

  // wave reduce both, then cross-wave via LDS, one store per block
  #pragma unroll
  for (int m = 32; m >= 1; m >>= 1) {
    esum += __shfl_xor(esum, m, 64);
    diag += __shfl_xor(diag, m, 64);
  }
  __shared__ float s_es[4], s_dg[4];
  const int wave = tid >> 6, lane = tid & 63;
  if (lane == 0) { s_es[wave] = esum; s_dg[wave] = diag; }
  __syncthreads();
  if (tid == 0)
    partial[blockIdx.x] = make_float2(s_es[0] + s_es[1] + s_es[2] + s_es[3],
                                      s_dg[0] + s_dg[1] + s_dg[2] + s_dg[3]);
}

// ---- Kernel 4: finalize (reduce 512 block partials in f64) -----------------
__global__ __launch_bounds__(256) void finalize_kernel(
    const float2* __restrict__ partial, float* __restrict__ out) {
  const int tid = threadIdx.x;
  double es = 0.0, dg = 0.0;
  #pragma unroll
  for (int t = 0; t < 2; ++t) {
    const float2 p = partial[tid + 256 * t];
    es += (double)p.x; dg += (double)p.y;
  }
  #pragma unroll
  for (int m = 32; m >= 1; m >>= 1) {
    es += __shfl_xor(es, m, 64);
    dg += __shfl_xor(dg, m, 64);
  }
  __shared__ double s_es[4], s_dg[4];
  const int wave = tid >> 6, lane = tid & 63;
  if (lane == 0) { s_es[wave] = es; s_dg[wave] = dg; }
  __syncthreads();
  if (tid == 0) {
    const double esT = s_es[0] + s_es[1] + s_es[2] + s_es[3];
    const double dgT = s_dg[0] + s_dg[1] + s_dg[2] + s_dg[3];
    const double n = (double)N_S;
    // mean T0 = diag(T1)/n + 1 ; term2 = expsum / n^2
    out[0] = (float)(dgT / n + 1.0 - esT / (n * n));
  }
}

extern "C" void kernel_launch(void* const* d_in, const int* in_sizes, int n_in,
                              void* d_out, int out_size, void* d_ws, size_t ws_size,
                              hipStream_t stream) {
  const float* x  = (const float*)d_in[0];
  const float* y  = (const float*)d_in[1];
  const float* W1 = (const float*)d_in[2];
  const float* b1 = (const float*)d_in[3];
  const float* W2 = (const float*)d_in[4];
  const float* b2 = (const float*)d_in[5];

  float*  At      = (float*)d_ws;                 // [HIDD][N_S]   1 MB
  float*  Yp      = At + HIDD * N_S;              // [N_S][HIDD]   1 MB
  float*  R       = Yp + N_S * HIDD;              // [N_S]
  float*  C       = R + N_S;                      // [N_S]
  float2* partial = (float2*)(C + N_S);           // 512 float2    4 KB

  dim3 g1(N_S / JBLK, 2);                         // 128 x 2 blocks
  proj_kernel<<<g1, 256, 0, stream>>>(x, y, W1, b1, At, Yp);
  rank1_kernel<<<8, 256, 0, stream>>>(At, Yp, W2, R, C);
  pair_kernel<<<(N_S / IBLK) * (N_S / JT), 256, 0, stream>>>(At, Yp, W2, R, C, b2, partial);
  finalize_kernel<<<1, 256, 0, stream>>>(partial, (float*)d_out);
}